// Round 7
// baseline (281.699 us; speedup 1.0000x reference)
//
#include <hip/hip_runtime.h>

#define NUM_USERS 50000
#define NUM_ITEMS 100000
#define NUM_NODES 150000   // NUM_USERS + NUM_ITEMS
#define D 64
#define NNZ 4800000
#define BATCH 4096
// light_out = acc/4 ; gamma = (sum_k u_k)·(sum_k i_k)/16 — acc never materialized:
// keep x0..x3 (fp16) and sum the 8 needed rows per batch element in k_gamma.

typedef __attribute__((ext_vector_type(4))) _Float16 half4;

// ---------------------------------------------------------------------------
// k_init: x0(fp16) = concat(user_emb, item_emb)
// ---------------------------------------------------------------------------
__global__ void k_init(const float* __restrict__ ue, const float* __restrict__ ie,
                       half4* __restrict__ x0) {
    const int total = NUM_NODES * D / 4;     // 2.4M groups of 4
    const int ulim  = NUM_USERS * D / 4;
    const float4* u4 = (const float4*)ue;
    const float4* i4 = (const float4*)ie;
    for (int i = blockIdx.x * blockDim.x + threadIdx.x; i < total;
         i += gridDim.x * blockDim.x) {
        float4 v = (i < ulim) ? u4[i] : i4[i - ulim];
        half4 h;
        h.x = (_Float16)v.x; h.y = (_Float16)v.y;
        h.z = (_Float16)v.z; h.w = (_Float16)v.w;
        x0[i] = h;
    }
}

// ---------------------------------------------------------------------------
// k_rowptr: rowptr[r] = lower_bound(rows, r)  (rows is sorted)
// ---------------------------------------------------------------------------
__global__ void k_rowptr(const int* __restrict__ rows, int* __restrict__ rowptr) {
    int r = blockIdx.x * blockDim.x + threadIdx.x;
    if (r > NUM_NODES) return;
    int lo = 0, hi = NNZ;
    while (lo < hi) {
        int mid = (lo + hi) >> 1;
        if (rows[mid] < r) lo = mid + 1; else hi = mid;
    }
    rowptr[r] = lo;
}

// ---------------------------------------------------------------------------
// k_spmm: 16 lanes per row, 4 rows/wave. x fp16 [150000][64]: one edge row =
// 128B = ONE cache line. fp32 accumulate, fp16 store.
// cols/vals loads and nxt store are NONTEMPORAL: they are single-use streams
// (38.4 MB + 19.2 MB per layer) that would otherwise evict the hot x lines
// from the 4 MB/XCD L2 (gather-miss term is the fabric-bound cost).
// ---------------------------------------------------------------------------
__global__ __launch_bounds__(256, 4) void k_spmm(const int* __restrict__ rowptr,
                       const int* __restrict__ cols,
                       const float* __restrict__ vals,
                       const half4* __restrict__ x,
                       half4* __restrict__ nxt) {
    const int wid   = (blockIdx.x * blockDim.x + threadIdx.x) >> 6;
    const int lane  = threadIdx.x & 63;
    const int l16   = lane & 15;
    const int gbase = lane & 48;           // 16-lane group base for shfl
    const int row   = wid * 4 + (lane >> 4);
    if (row >= NUM_NODES) return;          // group-uniform exit
    const int e0 = rowptr[row];
    const int e1 = rowptr[row + 1];
    float4 sum = make_float4(0.f, 0.f, 0.f, 0.f);

    // batch-0 metadata (nontemporal: streamed once)
    int   myc = 0;
    float myv = 0.f;
    {
        int idx0 = e0 + l16;
        if (idx0 < e1) {
            myc = __builtin_nontemporal_load(&cols[idx0]);
            myv = __builtin_nontemporal_load(&vals[idx0]);
        }
    }

    for (int e = e0; e < e1; e += 16) {
        int   c[16];
        float v[16];
#pragma unroll
        for (int t = 0; t < 16; ++t) {
            c[t] = __shfl(myc, gbase + t);
            v[t] = __shfl(myv, gbase + t);
        }
        // prefetch next batch's metadata (nontemporal); hides under gathers
        {
            int idx2 = e + 16 + l16;
            myc = 0; myv = 0.f;
            if (idx2 < e1) {
                myc = __builtin_nontemporal_load(&cols[idx2]);
                myv = __builtin_nontemporal_load(&vals[idx2]);
            }
        }
        half4 xv[16];
#pragma unroll
        for (int t = 0; t < 16; ++t)
            xv[t] = x[(size_t)c[t] * 16 + l16];   // 8B/lane, 128B per group
        __builtin_amdgcn_sched_barrier(0);         // keep gathers clustered
#pragma unroll
        for (int t = 0; t < 16; ++t) {
            sum.x += v[t] * (float)xv[t].x;
            sum.y += v[t] * (float)xv[t].y;
            sum.z += v[t] * (float)xv[t].z;
            sum.w += v[t] * (float)xv[t].w;
        }
    }
    half4 h;
    h.x = (_Float16)sum.x; h.y = (_Float16)sum.y;
    h.z = (_Float16)sum.z; h.w = (_Float16)sum.w;
    __builtin_nontemporal_store(h, &nxt[(size_t)row * 16 + l16]);
}

// ---------------------------------------------------------------------------
// k_gamma: 16 lanes per batch element (half4/lane), 4 elements/wave.
// su = sum_k x_k[u], si = sum_k x_k[i] (fp32); gamma = dot(su,si)/16.
// ---------------------------------------------------------------------------
__global__ void k_gamma(const half4* __restrict__ x0, const half4* __restrict__ x1,
                        const half4* __restrict__ x2, const half4* __restrict__ x3,
                        const int* __restrict__ users, const int* __restrict__ items,
                        float* __restrict__ out) {
    const int wid  = (blockIdx.x * blockDim.x + threadIdx.x) >> 6;
    const int lane = threadIdx.x & 63;
    const int l16  = lane & 15;
    const int b    = wid * 4 + (lane >> 4);
    if (b >= BATCH) return;
    const size_t ur = (size_t)users[b] * 16 + l16;
    const size_t ir = ((size_t)NUM_USERS + items[b]) * 16 + l16;
    half4 a0 = x0[ur], a1 = x1[ur], a2 = x2[ur], a3 = x3[ur];
    half4 c0 = x0[ir], c1 = x1[ir], c2 = x2[ir], c3 = x3[ir];
    float p = 0.f;
#pragma unroll
    for (int j = 0; j < 4; ++j) {
        float su = (float)a0[j] + (float)a1[j] + (float)a2[j] + (float)a3[j];
        float si = (float)c0[j] + (float)c1[j] + (float)c2[j] + (float)c3[j];
        p += su * si;
    }
    p += __shfl_xor(p, 8);
    p += __shfl_xor(p, 4);
    p += __shfl_xor(p, 2);
    p += __shfl_xor(p, 1);
    if (l16 == 0) out[b] = p * (1.0f / 16.0f);
}

extern "C" void kernel_launch(void* const* d_in, const int* in_sizes, int n_in,
                              void* d_out, int out_size, void* d_ws, size_t ws_size,
                              hipStream_t stream) {
    const float* ue    = (const float*)d_in[0];
    const float* ie    = (const float*)d_in[1];
    const int*   rows  = (const int*)d_in[2];
    const int*   cols  = (const int*)d_in[3];
    const float* vals  = (const float*)d_in[4];
    const int*   users = (const int*)d_in[5];
    const int*   items = (const int*)d_in[6];
    float*       out   = (float*)d_out;

    // workspace layout: rowptr | x0 | x1 | x2 | x3 (all fp16, 19.2 MB each)
    char* ws = (char*)d_ws;
    size_t off = (((size_t)(NUM_NODES + 1) * sizeof(int)) + 255) & ~(size_t)255;
    const size_t halfbuf = (size_t)NUM_NODES * D * sizeof(_Float16);
    int*   rowptr = (int*)ws;
    half4* x0     = (half4*)(ws + off);
    half4* x1     = (half4*)(ws + off + 1 * halfbuf);
    half4* x2     = (half4*)(ws + off + 2 * halfbuf);
    half4* x3     = (half4*)(ws + off + 3 * halfbuf);

    k_rowptr<<<(NUM_NODES + 1 + 255) / 256, 256, 0, stream>>>(rows, rowptr);
    k_init<<<2048, 256, 0, stream>>>(ue, ie, x0);

    // 3 SpMM layers; 4 rows per wave, 4 waves per block -> 16 rows/block
    const int spmm_blocks = NUM_NODES / 16;   // 150000/16 = 9375 exact
    k_spmm<<<spmm_blocks, 256, 0, stream>>>(rowptr, cols, vals, x0, x1);
    k_spmm<<<spmm_blocks, 256, 0, stream>>>(rowptr, cols, vals, x1, x2);
    k_spmm<<<spmm_blocks, 256, 0, stream>>>(rowptr, cols, vals, x2, x3);

    // gamma: 4 elements per wave, 16 per block -> 256 blocks
    k_gamma<<<BATCH / 16, 256, 0, stream>>>(x0, x1, x2, x3, users, items, out);
}

// Round 8
// 264.379 us; speedup vs baseline: 1.0655x; 1.0655x over previous
//
#include <hip/hip_runtime.h>

#define NUM_USERS 50000
#define NUM_ITEMS 100000
#define NUM_NODES 150000   // NUM_USERS + NUM_ITEMS
#define D 64
#define NNZ 4800000
#define BATCH 4096
// light_out = acc/4 ; gamma = (sum_k u_k)·(sum_k i_k)/16 — acc never materialized:
// keep x0..x3 (fp16) and sum the 8 needed rows per batch element in k_gamma.
//
// Perf model (R2/R4/R5/R6): spmm time = (FETCH+WRITE) / ~3.5 TB/s (beyond-L2
// random-line path), invariant to occupancy (37-65%) and ILP (5->16 deep).
// Remaining traffic/layer: 38.4 MB metadata + ~230 MB gather miss (floor ~154
// from 8-XCD replication) + 19.2 MB write. R7 showed nontemporal hints REGRESS
// (FETCH 268->285 MB): do not reintroduce them.

typedef __attribute__((ext_vector_type(4))) _Float16 half4;

// ---------------------------------------------------------------------------
// k_init: x0(fp16) = concat(user_emb, item_emb)
// ---------------------------------------------------------------------------
__global__ void k_init(const float* __restrict__ ue, const float* __restrict__ ie,
                       half4* __restrict__ x0) {
    const int total = NUM_NODES * D / 4;     // 2.4M groups of 4
    const int ulim  = NUM_USERS * D / 4;
    const float4* u4 = (const float4*)ue;
    const float4* i4 = (const float4*)ie;
    for (int i = blockIdx.x * blockDim.x + threadIdx.x; i < total;
         i += gridDim.x * blockDim.x) {
        float4 v = (i < ulim) ? u4[i] : i4[i - ulim];
        half4 h;
        h.x = (_Float16)v.x; h.y = (_Float16)v.y;
        h.z = (_Float16)v.z; h.w = (_Float16)v.w;
        x0[i] = h;
    }
}

// ---------------------------------------------------------------------------
// k_rowptr: rowptr[r] = lower_bound(rows, r)  (rows is sorted)
// ---------------------------------------------------------------------------
__global__ void k_rowptr(const int* __restrict__ rows, int* __restrict__ rowptr) {
    int r = blockIdx.x * blockDim.x + threadIdx.x;
    if (r > NUM_NODES) return;
    int lo = 0, hi = NNZ;
    while (lo < hi) {
        int mid = (lo + hi) >> 1;
        if (rows[mid] < r) lo = mid + 1; else hi = mid;
    }
    rowptr[r] = lo;
}

// ---------------------------------------------------------------------------
// k_spmm: 16 lanes per row, 4 rows/wave. x fp16 [150000][64]: one edge row =
// 128B = ONE cache line. fp32 accumulate, fp16 store. Metadata shfl-broadcast
// per 16-edge batch + next-batch prefetch; sched_barrier pins the 16 gathers
// ahead of the FMAs (without it the compiler re-fuses to ~5-deep clusters).
// ---------------------------------------------------------------------------
__global__ __launch_bounds__(256, 4) void k_spmm(const int* __restrict__ rowptr,
                       const int* __restrict__ cols,
                       const float* __restrict__ vals,
                       const half4* __restrict__ x,
                       half4* __restrict__ nxt) {
    const int wid   = (blockIdx.x * blockDim.x + threadIdx.x) >> 6;
    const int lane  = threadIdx.x & 63;
    const int l16   = lane & 15;
    const int gbase = lane & 48;           // 16-lane group base for shfl
    const int row   = wid * 4 + (lane >> 4);
    if (row >= NUM_NODES) return;          // group-uniform exit
    const int e0 = rowptr[row];
    const int e1 = rowptr[row + 1];
    float4 sum = make_float4(0.f, 0.f, 0.f, 0.f);

    // batch-0 metadata
    int   idx0 = e0 + l16;
    bool  ok0  = idx0 < e1;
    int   myc  = ok0 ? cols[idx0] : 0;
    float myv  = ok0 ? vals[idx0] : 0.f;

    for (int e = e0; e < e1; e += 16) {
        int   c[16];
        float v[16];
#pragma unroll
        for (int t = 0; t < 16; ++t) {
            c[t] = __shfl(myc, gbase + t);
            v[t] = __shfl(myv, gbase + t);
        }
        // prefetch next batch's metadata; hides under the gathers
        {
            int  idx2 = e + 16 + l16;
            bool ok2  = idx2 < e1;
            myc = ok2 ? cols[idx2] : 0;
            myv = ok2 ? vals[idx2] : 0.f;
        }
        half4 xv[16];
#pragma unroll
        for (int t = 0; t < 16; ++t)
            xv[t] = x[(size_t)c[t] * 16 + l16];   // 8B/lane, 128B per group
        __builtin_amdgcn_sched_barrier(0);         // keep gathers clustered
#pragma unroll
        for (int t = 0; t < 16; ++t) {
            sum.x += v[t] * (float)xv[t].x;
            sum.y += v[t] * (float)xv[t].y;
            sum.z += v[t] * (float)xv[t].z;
            sum.w += v[t] * (float)xv[t].w;
        }
    }
    half4 h;
    h.x = (_Float16)sum.x; h.y = (_Float16)sum.y;
    h.z = (_Float16)sum.z; h.w = (_Float16)sum.w;
    nxt[(size_t)row * 16 + l16] = h;
}

// ---------------------------------------------------------------------------
// k_gamma: 16 lanes per batch element (half4/lane), 4 elements/wave.
// su = sum_k x_k[u], si = sum_k x_k[i] (fp32); gamma = dot(su,si)/16.
// ---------------------------------------------------------------------------
__global__ void k_gamma(const half4* __restrict__ x0, const half4* __restrict__ x1,
                        const half4* __restrict__ x2, const half4* __restrict__ x3,
                        const int* __restrict__ users, const int* __restrict__ items,
                        float* __restrict__ out) {
    const int wid  = (blockIdx.x * blockDim.x + threadIdx.x) >> 6;
    const int lane = threadIdx.x & 63;
    const int l16  = lane & 15;
    const int b    = wid * 4 + (lane >> 4);
    if (b >= BATCH) return;
    const size_t ur = (size_t)users[b] * 16 + l16;
    const size_t ir = ((size_t)NUM_USERS + items[b]) * 16 + l16;
    half4 a0 = x0[ur], a1 = x1[ur], a2 = x2[ur], a3 = x3[ur];
    half4 c0 = x0[ir], c1 = x1[ir], c2 = x2[ir], c3 = x3[ir];
    float p = 0.f;
#pragma unroll
    for (int j = 0; j < 4; ++j) {
        float su = (float)a0[j] + (float)a1[j] + (float)a2[j] + (float)a3[j];
        float si = (float)c0[j] + (float)c1[j] + (float)c2[j] + (float)c3[j];
        p += su * si;
    }
    p += __shfl_xor(p, 8);
    p += __shfl_xor(p, 4);
    p += __shfl_xor(p, 2);
    p += __shfl_xor(p, 1);
    if (l16 == 0) out[b] = p * (1.0f / 16.0f);
}

extern "C" void kernel_launch(void* const* d_in, const int* in_sizes, int n_in,
                              void* d_out, int out_size, void* d_ws, size_t ws_size,
                              hipStream_t stream) {
    const float* ue    = (const float*)d_in[0];
    const float* ie    = (const float*)d_in[1];
    const int*   rows  = (const int*)d_in[2];
    const int*   cols  = (const int*)d_in[3];
    const float* vals  = (const float*)d_in[4];
    const int*   users = (const int*)d_in[5];
    const int*   items = (const int*)d_in[6];
    float*       out   = (float*)d_out;

    // workspace layout: rowptr | x0 | x1 | x2 | x3 (all fp16, 19.2 MB each)
    char* ws = (char*)d_ws;
    size_t off = (((size_t)(NUM_NODES + 1) * sizeof(int)) + 255) & ~(size_t)255;
    const size_t halfbuf = (size_t)NUM_NODES * D * sizeof(_Float16);
    int*   rowptr = (int*)ws;
    half4* x0     = (half4*)(ws + off);
    half4* x1     = (half4*)(ws + off + 1 * halfbuf);
    half4* x2     = (half4*)(ws + off + 2 * halfbuf);
    half4* x3     = (half4*)(ws + off + 3 * halfbuf);

    k_rowptr<<<(NUM_NODES + 1 + 255) / 256, 256, 0, stream>>>(rows, rowptr);
    k_init<<<2048, 256, 0, stream>>>(ue, ie, x0);

    // 3 SpMM layers; 4 rows per wave, 4 waves per block -> 16 rows/block
    const int spmm_blocks = NUM_NODES / 16;   // 150000/16 = 9375 exact
    k_spmm<<<spmm_blocks, 256, 0, stream>>>(rowptr, cols, vals, x0, x1);
    k_spmm<<<spmm_blocks, 256, 0, stream>>>(rowptr, cols, vals, x1, x2);
    k_spmm<<<spmm_blocks, 256, 0, stream>>>(rowptr, cols, vals, x2, x3);

    // gamma: 4 elements per wave, 16 per block -> 256 blocks
    k_gamma<<<BATCH / 16, 256, 0, stream>>>(x0, x1, x2, x3, users, items, out);
}